// Round 8
// baseline (200.786 us; speedup 1.0000x reference)
//
#include <hip/hip_runtime.h>
#include <hip/hip_bf16.h>
#include <stdint.h>

typedef __bf16 bf16_t;
typedef bf16_t bf16x4 __attribute__((ext_vector_type(4)));
typedef bf16_t bf16x8 __attribute__((ext_vector_type(8)));
typedef float  f32x4  __attribute__((ext_vector_type(4)));

#define B_   4
#define T_   1024
#define C_   1024
#define H_   16

__device__ __forceinline__ f32x4 mfma_bf16(bf16x8 a, bf16x8 b, f32x4 c) {
  return __builtin_amdgcn_mfma_f32_16x16x32_bf16(a, b, c, 0, 0, 0);
}

__device__ __forceinline__ void async16(const bf16_t* g, bf16_t* l) {
  __builtin_amdgcn_global_load_lds(
      (__attribute__((address_space(1))) void*)(uintptr_t)g,
      (__attribute__((address_space(3))) void*)l, 16, 0, 0);
}

// ---------------------------------------------------------------- convert
__global__ __launch_bounds__(256) void convert_f32_bf16(
    const float* __restrict__ in, bf16_t* __restrict__ out, int n4)
{
  const int i = blockIdx.x * 256 + threadIdx.x;
  if (i >= n4) return;
  const float4 v = *(const float4*)(in + (size_t)i * 4);
  bf16x4 o;
  o[0] = (bf16_t)v.x; o[1] = (bf16_t)v.y; o[2] = (bf16_t)v.z; o[3] = (bf16_t)v.w;
  *(bf16x4*)(out + (size_t)i * 4) = o;
}

// ---------------------------------------------------------------- transpose
__global__ __launch_bounds__(256) void transpose4_f32_bf16(
    const float* __restrict__ a0, const float* __restrict__ a1,
    const float* __restrict__ a2, const float* __restrict__ a3,
    bf16_t* __restrict__ out)
{
  __shared__ bf16_t tile[32][33];
  const int z = blockIdx.z;
  const float* in = (z == 0) ? a0 : (z == 1) ? a1 : (z == 2) ? a2 : a3;
  bf16_t* o = out + ((size_t)z << 20);
  const int n0 = blockIdx.x * 32, k0 = blockIdx.y * 32;
  const int x = threadIdx.x & 31, y4 = (threadIdx.x >> 5) * 4;
#pragma unroll
  for (int i = 0; i < 4; ++i)
    tile[y4 + i][x] = (bf16_t)in[(size_t)(k0 + y4 + i) * 1024 + n0 + x];
  __syncthreads();
#pragma unroll
  for (int i = 0; i < 4; ++i)
    o[(size_t)(n0 + y4 + i) * 1024 + k0 + x] = tile[x][y4 + i];
}

// ---------------------------------------------------------------- transpose_v
__global__ __launch_bounds__(256) void transpose_v(
    const bf16_t* __restrict__ qkvb, bf16_t* __restrict__ vT)
{
  __shared__ bf16_t tile[64][66];
  const int bid = blockIdx.x;
  const int kb = bid & 15, bh = bid >> 4;
  const int b = bh >> 4, h = bh & 15;
  const int t = threadIdx.x;
  {
    const int key = t & 63, fc = (t >> 6) * 16;
    const bf16_t* src =
        qkvb + (size_t)(b * 1024 + kb * 64 + key) * 3072 + 2048 + h * 64 + fc;
    bf16x8 v0 = *(const bf16x8*)src;
    bf16x8 v1 = *(const bf16x8*)(src + 8);
#pragma unroll
    for (int j = 0; j < 8; ++j) {
      tile[fc + j][key]     = v0[j];
      tile[fc + 8 + j][key] = v1[j];
    }
  }
  __syncthreads();
  {
    const int f = t & 63, kc = (t >> 6) * 16;
    bf16x8 o0, o1;
#pragma unroll
    for (int j = 0; j < 8; ++j) {
      o0[j] = tile[f][kc + j];
      o1[j] = tile[f][kc + 8 + j];
    }
    bf16_t* dst = vT + ((size_t)bh * 64 + f) * 1024 + kb * 64 + kc;
    *(bf16x8*)dst = o0;
    *(bf16x8*)(dst + 8) = o1;
  }
}

// ---------------------------------------------------------------- bias_eff
__global__ __launch_bounds__(256) void bias_eff_kernel(
    const float* __restrict__ cb,
    const float* __restrict__ w0, const float* __restrict__ w1,
    const float* __restrict__ w2,
    const float* __restrict__ b0, const float* __restrict__ b1,
    const float* __restrict__ b2,
    float* __restrict__ out)
{
  const int j = blockIdx.x * 256 + threadIdx.x;
  const int s = j >> 10, jj = j & 1023;
  const float* w  = (s == 0) ? w0 : (s == 1) ? w1 : w2;
  const float* sb = (s == 0) ? b0 : (s == 1) ? b1 : b2;
  const int c0 = blockIdx.y * 128;
  float acc = (blockIdx.y == 0) ? sb[jj] : 0.0f;
  for (int c = c0; c < c0 + 128; ++c)
    acc += cb[s * 1024 + c] * w[(size_t)c * 1024 + jj];
  atomicAdd(&out[j], acc);
}

// ---------------------------------------------------------------- GEMM
template <typename OT>
__global__ __launch_bounds__(256) void gemm_bt_bias(
    const bf16_t* __restrict__ A, int lda,
    const bf16_t* __restrict__ Bt, int ldb,
    const float* __restrict__ bias,
    OT* __restrict__ C, int ldc,
    int K, int nTilesN, int blocksPerMat,
    int strideA, int strideB, int strideC)
{
  __shared__ __align__(16) bf16_t As[2][128 * 32];
  __shared__ __align__(16) bf16_t Bs[2][128 * 32];
  const int s   = blockIdx.x / blocksPerMat;
  const int bid = blockIdx.x % blocksPerMat;
  A  += (size_t)s * strideA;
  Bt += (size_t)s * strideB;
  C  += (size_t)s * strideC;
  const int mt = bid / nTilesN, nt = bid % nTilesN;
  const int m0 = mt * 128, n0 = nt * 128;
  const int tid = threadIdx.x;
  const int lane = tid & 63;
  const int lr = lane & 15, lg = lane >> 4;
  const int wid = tid >> 6;
  const int wr = wid >> 1, wc = wid & 1;

  f32x4 acc[4][4];
#pragma unroll
  for (int m = 0; m < 4; ++m)
#pragma unroll
    for (int n = 0; n < 4; ++n) acc[m][n] = (f32x4){0.f, 0.f, 0.f, 0.f};

  const int nk = K >> 5;
  int cur = 0;
#pragma unroll
  for (int p = 0; p < 2; ++p) {
    int c = p * 256 + tid;
    int row = c >> 2, col = (c & 3) << 3;
    async16(A + (size_t)(m0 + row) * lda + col, &As[0][row * 32 + col]);
    async16(Bt + (size_t)(n0 + row) * ldb + col, &Bs[0][row * 32 + col]);
  }
  __syncthreads();

  for (int t = 0; t < nk; ++t) {
    if (t + 1 < nk) {
      const int k0 = (t + 1) << 5;
#pragma unroll
      for (int p = 0; p < 2; ++p) {
        int c = p * 256 + tid;
        int row = c >> 2, col = (c & 3) << 3;
        async16(A + (size_t)(m0 + row) * lda + k0 + col, &As[cur ^ 1][row * 32 + col]);
        async16(Bt + (size_t)(n0 + row) * ldb + k0 + col, &Bs[cur ^ 1][row * 32 + col]);
      }
    }
    bf16x8 af[4], bfr[4];
#pragma unroll
    for (int m = 0; m < 4; ++m)
      af[m] = *(const bf16x8*)&As[cur][(wr * 64 + m * 16 + lr) * 32 + lg * 8];
#pragma unroll
    for (int n = 0; n < 4; ++n)
      bfr[n] = *(const bf16x8*)&Bs[cur][(wc * 64 + n * 16 + lr) * 32 + lg * 8];
#pragma unroll
    for (int m = 0; m < 4; ++m)
#pragma unroll
      for (int n = 0; n < 4; ++n)
        acc[m][n] = mfma_bf16(af[m], bfr[n], acc[m][n]);
    __syncthreads();
    cur ^= 1;
  }

#pragma unroll
  for (int n = 0; n < 4; ++n) {
    const int col = n0 + wc * 64 + n * 16 + lr;
    const float bv = bias ? bias[col] : 0.0f;
#pragma unroll
    for (int m = 0; m < 4; ++m) {
      const int row = m0 + wr * 64 + m * 16 + lg * 4;
#pragma unroll
      for (int r = 0; r < 4; ++r)
        C[(size_t)(row + r) * ldc + col] = (OT)(acc[m][n][r] + bv);
    }
  }
}

// ---------------------------------------------------------------- attention
// Split-K pair-balanced flash attention with register-double-buffered
// K prefetch (this wave's next key-tile loads during current softmax/PV)
// and ILP-tree softmax. XCD decode keeps each (b,h) on one XCD (L2-resident).
__global__ __launch_bounds__(256) void attn_kernel(
    const bf16_t* __restrict__ qkv, const bf16_t* __restrict__ vT,
    bf16_t* __restrict__ o)
{
  __shared__ __align__(16) bf16_t Ps[4][16][72];
  __shared__ float Mb[2][64][19];
  const int LD = 3072;
  const bf16_t* q = qkv;
  const bf16_t* k = qkv + 1024;

  const int raw = blockIdx.x;
  const int xcd = raw & 7, idx = raw >> 3;
  const int bh = (idx >> 4) * 8 + xcd;
  const int g  = idx & 15;
  const int b = bh >> 4, h = bh & 15;

  const int tid = threadIdx.x;
  const int lane = tid & 63;
  const int lr = lane & 15, lg = lane >> 4;
  const int w = tid >> 6;
  const int pr = w >> 1;                   // pair slot {0,1}
  const int t  = w & 1;                    // key-split half
  const int s  = g * 2 + pr;               // task in [0,32)

  const bf16_t* kbase = k + (size_t)(b * T_) * LD + h * 64;
  const bf16_t* vbase = vT + (size_t)bh * 64 * T_;

#pragma unroll
  for (int pass = 0; pass < 2; ++pass) {
    const int j = pass ? (63 - s) : s;
    const int myq = j * 16 + lr;
    const int nIter = (j >> 2) + 1;

    bf16x8 qf[2];
    {
      const size_t qr = (size_t)(b * T_ + myq) * LD + h * 64;
      qf[0] = *(const bf16x8*)&q[qr + lg * 8];
      qf[1] = *(const bf16x8*)&q[qr + 32 + lg * 8];
    }

    float mi = -3.0e38f, li = 0.0f;
    f32x4 acc[4];
#pragma unroll
    for (int nf = 0; nf < 4; ++nf) acc[nf] = (f32x4){0.f, 0.f, 0.f, 0.f};

    bf16x8 kfA[4][2], kfB[4][2];

    auto load_kf = [&](bf16x8 (&KF)[4][2], int kv0) {
#pragma unroll
      for (int kg = 0; kg < 4; ++kg)
#pragma unroll
        for (int kk = 0; kk < 2; ++kk)
          KF[kg][kk] = *(const bf16x8*)
              &kbase[(size_t)(kv0 + kg * 16 + lr) * LD + kk * 32 + lg * 8];
    };

    auto step = [&](bf16x8 (&KF)[4][2], int kv0) {
      // V loads issued first: latency hides under QKT + softmax
      bf16x8 vf[2][4];
#pragma unroll
      for (int kk = 0; kk < 2; ++kk)
#pragma unroll
        for (int nf = 0; nf < 4; ++nf)
          vf[kk][nf] = *(const bf16x8*)
              &vbase[(size_t)(nf * 16 + lr) * T_ + kv0 + kk * 32 + lg * 8];

      // S^T: lane holds S[q=myq][key=kv0+kg*16+lg*4+r]
      f32x4 sfr[4];
      __builtin_amdgcn_s_setprio(1);
#pragma unroll
      for (int kg = 0; kg < 4; ++kg) {
        f32x4 z = (f32x4){0.f, 0.f, 0.f, 0.f};
        z = mfma_bf16(KF[kg][0], qf[0], z);
        z = mfma_bf16(KF[kg][1], qf[1], z);
        sfr[kg] = z;
      }
      __builtin_amdgcn_s_setprio(0);

      // scale (net 1/64), causal mask; 4-way ILP max/sum trees
      float sv[4][4];
      float pm[4];
#pragma unroll
      for (int kg = 0; kg < 4; ++kg) {
        const int keyb = kv0 + kg * 16 + lg * 4;
        pm[kg] = -3.0e38f;
#pragma unroll
        for (int r = 0; r < 4; ++r) {
          float xx = sfr[kg][r] * 0.015625f;
          if (keyb + r > myq) xx = -3.0e38f;
          sv[kg][r] = xx;
          pm[kg] = fmaxf(pm[kg], xx);
        }
      }
      float pmax = fmaxf(fmaxf(pm[0], pm[1]), fmaxf(pm[2], pm[3]));
      pmax = fmaxf(pmax, __shfl_xor(pmax, 16));
      pmax = fmaxf(pmax, __shfl_xor(pmax, 32));
      const float mnew = fmaxf(mi, pmax);
      const float fr = __expf(mi - mnew);
      mi = mnew;
      float ps[4];
#pragma unroll
      for (int kg = 0; kg < 4; ++kg) {
        float p0 = __expf(sv[kg][0] - mi);
        float p1 = __expf(sv[kg][1] - mi);
        float p2 = __expf(sv[kg][2] - mi);
        float p3 = __expf(sv[kg][3] - mi);
        sv[kg][0] = p0; sv[kg][1] = p1; sv[kg][2] = p2; sv[kg][3] = p3;
        ps[kg] = (p0 + p1) + (p2 + p3);
      }
      float psum = (ps[0] + ps[1]) + (ps[2] + ps[3]);
      psum += __shfl_xor(psum, 16);
      psum += __shfl_xor(psum, 32);
      li = li * fr + psum;
#pragma unroll
      for (int nf = 0; nf < 4; ++nf)
#pragma unroll
        for (int r = 0; r < 4; ++r) acc[nf][r] *= fr;

      // P -> LDS (b64 packed), within-wave round trip (no barrier)
#pragma unroll
      for (int kg = 0; kg < 4; ++kg) {
        bf16x4 p4;
#pragma unroll
        for (int r = 0; r < 4; ++r) p4[r] = (bf16_t)sv[kg][r];
        *(bf16x4*)&Ps[w][lr][kg * 16 + lg * 4] = p4;
      }

      // O^T += V^T @ P^T
      __builtin_amdgcn_s_setprio(1);
#pragma unroll
      for (int kk = 0; kk < 2; ++kk) {
        bf16x8 pf = *(const bf16x8*)&Ps[w][lr][kk * 32 + lg * 8];
#pragma unroll
        for (int nf = 0; nf < 4; ++nf)
          acc[nf] = mfma_bf16(vf[kk][nf], pf, acc[nf]);
      }
      __builtin_amdgcn_s_setprio(0);
    };

    // software-pipelined split-K loop: prefetch kf for it+2
    if (t < nIter) load_kf(kfA, t << 6);
    int parity = 0;
    for (int it = t; it < nIter; it += 2) {
      const int itn = it + 2;
      if (parity == 0) {
        if (itn < nIter) load_kf(kfB, itn << 6);
        step(kfA, it << 6);
      } else {
        if (itn < nIter) load_kf(kfA, itn << 6);
        step(kfB, it << 6);
      }
      parity ^= 1;
    }

    // merge split-K partners
    if (t == 1) {
#pragma unroll
      for (int nf = 0; nf < 4; ++nf)
#pragma unroll
        for (int r = 0; r < 4; ++r) Mb[pr][lane][nf * 4 + r] = acc[nf][r];
      Mb[pr][lane][16] = mi;
      Mb[pr][lane][17] = li;
    }
    __syncthreads();
    if (t == 0) {
      const float m1 = Mb[pr][lane][16];
      const float l1 = Mb[pr][lane][17];
      const float m  = fmaxf(mi, m1);
      const float e0 = __expf(mi - m);
      const float e1 = __expf(m1 - m);
      const float inv = 1.0f / (li * e0 + l1 * e1);
#pragma unroll
      for (int nf = 0; nf < 4; ++nf) {
        bf16x4 o4;
#pragma unroll
        for (int r = 0; r < 4; ++r)
          o4[r] = (bf16_t)((acc[nf][r] * e0 + Mb[pr][lane][nf * 4 + r] * e1) * inv);
        *(bf16x4*)&o[(size_t)(b * T_ + myq) * C_ + h * 64 + nf * 16 + lg * 4] = o4;
      }
    }
    __syncthreads();
  }
}

// ---------------------------------------------------------------- layernorm
__global__ __launch_bounds__(256) void ln_kernel(
    const bf16_t* __restrict__ in,
    const float* __restrict__ g,
    const float* __restrict__ be,
    bf16_t* __restrict__ out)
{
  const int row = blockIdx.x * 4 + (threadIdx.x >> 6);
  const int lane = threadIdx.x & 63;
  const bf16_t* p = in + (size_t)row * C_ + lane * 16;
  bf16x8 a0 = *(const bf16x8*)p;
  bf16x8 a1 = *(const bf16x8*)(p + 8);
  float xs[16];
#pragma unroll
  for (int j = 0; j < 8; ++j) { xs[j] = (float)a0[j]; xs[8 + j] = (float)a1[j]; }
  float sum = 0.f, sq = 0.f;
#pragma unroll
  for (int j = 0; j < 16; ++j) { sum += xs[j]; sq += xs[j] * xs[j]; }
#pragma unroll
  for (int dd = 1; dd < 64; dd <<= 1) {
    sum += __shfl_xor(sum, dd);
    sq  += __shfl_xor(sq, dd);
  }
  const float mean = sum * (1.0f / 1024.0f);
  const float var  = sq * (1.0f / 1024.0f) - mean * mean;
  const float rstd = rsqrtf(var + 1e-5f);
  float gv[16], bv[16];
#pragma unroll
  for (int j = 0; j < 4; ++j) {
    *(float4*)&gv[j * 4] = *(const float4*)(g  + lane * 16 + j * 4);
    *(float4*)&bv[j * 4] = *(const float4*)(be + lane * 16 + j * 4);
  }
  bf16x8 o0, o1;
#pragma unroll
  for (int j = 0; j < 8; ++j) {
    o0[j] = (bf16_t)((xs[j] - mean) * rstd * gv[j] + bv[j]);
    o1[j] = (bf16_t)((xs[8 + j] - mean) * rstd * gv[8 + j] + bv[8 + j]);
  }
  bf16_t* op = out + (size_t)row * C_ + lane * 16;
  *(bf16x8*)op = o0;
  *(bf16x8*)(op + 8) = o1;
}

// ---------------------------------------------------------------- launch
extern "C" void kernel_launch(void* const* d_in, const int* in_sizes, int n_in,
                              void* d_out, int out_size, void* d_ws, size_t ws_size,
                              hipStream_t stream)
{
  const float* x        = (const float*)d_in[0];
  const float* c_attn_w = (const float*)d_in[1];
  const float* c_attn_b = (const float*)d_in[2];
  const float* q_w      = (const float*)d_in[3];
  const float* q_b      = (const float*)d_in[4];
  const float* k_w      = (const float*)d_in[5];
  const float* k_b      = (const float*)d_in[6];
  const float* v_w      = (const float*)d_in[7];
  const float* v_b      = (const float*)d_in[8];
  const float* ln_g     = (const float*)d_in[9];
  const float* ln_b     = (const float*)d_in[10];
  const float* out_w    = (const float*)d_in[11];
  const float* out_b    = (const float*)d_in[12];

  char* ws = (char*)d_ws;
  bf16_t* qkvb      = (bf16_t*)(ws + 0);          // [4096][3072]
  bf16_t* xb        = (bf16_t*)(ws + 25165824);   // [4096][1024] dead after qkv
  bf16_t* lnb       = (bf16_t*)(ws + 25165824);   // overlays xb, used late
  bf16_t* WsT4      = (bf16_t*)(ws + 33554432);   // 4 slabs of 1M bf16
  bf16_t* c_attn_wb = (bf16_t*)(ws + 41943040);   // [1024][3072]
  bf16_t* Wt_eff    = (bf16_t*)(ws + 48234496);   // [3072][1024]
  float*  bias_eff  = (float*)(ws + 54525952);    // [3072]
  bf16_t* vT        = (bf16_t*)(ws + 54538240);   // [64*64][1024] = 8 MB

  convert_f32_bf16<<<dim3(4096), 256, 0, stream>>>(x, xb, 1048576);
  convert_f32_bf16<<<dim3(3072), 256, 0, stream>>>(c_attn_w, c_attn_wb, 786432);

  transpose4_f32_bf16<<<dim3(32, 32, 4), 256, 0, stream>>>(
      q_w, k_w, v_w, out_w, WsT4);

  gemm_bt_bias<bf16_t><<<dim3(192), 256, 0, stream>>>(
      WsT4, 1024, c_attn_wb, 3072, nullptr, Wt_eff, 1024,
      1024, 8, 64, 1 << 20, 1024, 1 << 20);

  hipMemsetAsync(bias_eff, 0, 3072 * sizeof(float), stream);
  bias_eff_kernel<<<dim3(12, 8), 256, 0, stream>>>(
      c_attn_b, q_w, k_w, v_w, q_b, k_b, v_b, bias_eff);

  gemm_bt_bias<bf16_t><<<dim3(768), 256, 0, stream>>>(
      xb, 1024, Wt_eff, 1024, bias_eff, qkvb, 3072, 1024, 24, 768, 0, 0, 0);

  transpose_v<<<dim3(1024), 256, 0, stream>>>(qkvb, vT);

  attn_kernel<<<dim3(1024), 256, 0, stream>>>(qkvb, vT, (bf16_t*)d_out);

  ln_kernel<<<dim3(1024), 256, 0, stream>>>((const bf16_t*)d_out, ln_g, ln_b, lnb);

  gemm_bt_bias<float><<<dim3(256), 256, 0, stream>>>(
      lnb, 1024, WsT4 + (size_t)3 * (1 << 20), 1024, out_b,
      (float*)d_out, 1024, 1024, 8, 256, 0, 0, 0);
}

// Round 9
// 155.699 us; speedup vs baseline: 1.2896x; 1.2896x over previous
//
#include <hip/hip_runtime.h>
#include <hip/hip_bf16.h>
#include <stdint.h>

typedef __bf16 bf16_t;
typedef bf16_t bf16x4 __attribute__((ext_vector_type(4)));
typedef bf16_t bf16x8 __attribute__((ext_vector_type(8)));
typedef float  f32x4  __attribute__((ext_vector_type(4)));

#define B_   4
#define T_   1024
#define C_   1024
#define H_   16

__device__ __forceinline__ f32x4 mfma_bf16(bf16x8 a, bf16x8 b, f32x4 c) {
  return __builtin_amdgcn_mfma_f32_16x16x32_bf16(a, b, c, 0, 0, 0);
}

__device__ __forceinline__ void async16(const bf16_t* g, bf16_t* l) {
  __builtin_amdgcn_global_load_lds(
      (__attribute__((address_space(1))) void*)(uintptr_t)g,
      (__attribute__((address_space(3))) void*)l, 16, 0, 0);
}

// ---------------------------------------------------------------- convert
__global__ __launch_bounds__(256) void convert_f32_bf16(
    const float* __restrict__ in, bf16_t* __restrict__ out, int n4)
{
  const int i = blockIdx.x * 256 + threadIdx.x;
  if (i >= n4) return;
  const float4 v = *(const float4*)(in + (size_t)i * 4);
  bf16x4 o;
  o[0] = (bf16_t)v.x; o[1] = (bf16_t)v.y; o[2] = (bf16_t)v.z; o[3] = (bf16_t)v.w;
  *(bf16x4*)(out + (size_t)i * 4) = o;
}

// ---------------------------------------------------------------- transpose
__global__ __launch_bounds__(256) void transpose4_f32_bf16(
    const float* __restrict__ a0, const float* __restrict__ a1,
    const float* __restrict__ a2, const float* __restrict__ a3,
    bf16_t* __restrict__ out)
{
  __shared__ bf16_t tile[32][33];
  const int z = blockIdx.z;
  const float* in = (z == 0) ? a0 : (z == 1) ? a1 : (z == 2) ? a2 : a3;
  bf16_t* o = out + ((size_t)z << 20);
  const int n0 = blockIdx.x * 32, k0 = blockIdx.y * 32;
  const int x = threadIdx.x & 31, y4 = (threadIdx.x >> 5) * 4;
#pragma unroll
  for (int i = 0; i < 4; ++i)
    tile[y4 + i][x] = (bf16_t)in[(size_t)(k0 + y4 + i) * 1024 + n0 + x];
  __syncthreads();
#pragma unroll
  for (int i = 0; i < 4; ++i)
    o[(size_t)(n0 + y4 + i) * 1024 + k0 + x] = tile[x][y4 + i];
}

// ---------------------------------------------------------------- v_frag
// qkvb v-slice -> vfrag in MFMA-fragment-linear order:
// vfrag[((bh*16+it)*8 + kk*4+nf)*512 + lane*8 + j]
//   = V^T[nf*16+(lane&15)][it*64 + kk*32 + (lane>>4)*8 + j]
__global__ __launch_bounds__(256) void transpose_v(
    const bf16_t* __restrict__ qkvb, bf16_t* __restrict__ vfrag)
{
  __shared__ bf16_t tile[64][66];   // tile[f][key]
  const int bid = blockIdx.x;
  const int kb = bid & 15, bh = bid >> 4;
  const int b = bh >> 4, h = bh & 15;
  const int t = threadIdx.x;
  {
    const int key = t & 63, fc = (t >> 6) * 16;
    const bf16_t* src =
        qkvb + (size_t)(b * 1024 + kb * 64 + key) * 3072 + 2048 + h * 64 + fc;
    bf16x8 v0 = *(const bf16x8*)src;
    bf16x8 v1 = *(const bf16x8*)(src + 8);
#pragma unroll
    for (int j = 0; j < 8; ++j) {
      tile[fc + j][key]     = v0[j];
      tile[fc + 8 + j][key] = v1[j];
    }
  }
  __syncthreads();
#pragma unroll
  for (int ww = 0; ww < 2; ++ww) {
    const int g = t * 2 + ww;              // [0,512)
    const int chunk = g >> 6;              // kk*4+nf
    const int lane2 = g & 63;
    const int lr2 = lane2 & 15, lg2 = lane2 >> 4;
    const int kk = chunk >> 2, nf = chunk & 3;
    const int f = nf * 16 + lr2;
    const int key0 = kk * 32 + lg2 * 8;
    bf16x8 val;
#pragma unroll
    for (int j = 0; j < 8; ++j) val[j] = tile[f][key0 + j];
    *(bf16x8*)&vfrag[(((size_t)bh * 16 + kb) * 8 + chunk) * 512 + lane2 * 8] = val;
  }
}

// ---------------------------------------------------------------- bias_eff
__global__ __launch_bounds__(256) void bias_eff_kernel(
    const float* __restrict__ cb,
    const float* __restrict__ w0, const float* __restrict__ w1,
    const float* __restrict__ w2,
    const float* __restrict__ b0, const float* __restrict__ b1,
    const float* __restrict__ b2,
    float* __restrict__ out)
{
  const int j = blockIdx.x * 256 + threadIdx.x;
  const int s = j >> 10, jj = j & 1023;
  const float* w  = (s == 0) ? w0 : (s == 1) ? w1 : w2;
  const float* sb = (s == 0) ? b0 : (s == 1) ? b1 : b2;
  const int c0 = blockIdx.y * 128;
  float acc = (blockIdx.y == 0) ? sb[jj] : 0.0f;
  for (int c = c0; c < c0 + 128; ++c)
    acc += cb[s * 1024 + c] * w[(size_t)c * 1024 + jj];
  atomicAdd(&out[j], acc);
}

// ---------------------------------------------------------------- GEMM
template <typename OT>
__global__ __launch_bounds__(256) void gemm_bt_bias(
    const bf16_t* __restrict__ A, int lda,
    const bf16_t* __restrict__ Bt, int ldb,
    const float* __restrict__ bias,
    OT* __restrict__ C, int ldc,
    int K, int nTilesN, int blocksPerMat,
    int strideA, int strideB, int strideC)
{
  __shared__ __align__(16) bf16_t As[2][128 * 32];
  __shared__ __align__(16) bf16_t Bs[2][128 * 32];
  const int s   = blockIdx.x / blocksPerMat;
  const int bid = blockIdx.x % blocksPerMat;
  A  += (size_t)s * strideA;
  Bt += (size_t)s * strideB;
  C  += (size_t)s * strideC;
  const int mt = bid / nTilesN, nt = bid % nTilesN;
  const int m0 = mt * 128, n0 = nt * 128;
  const int tid = threadIdx.x;
  const int lane = tid & 63;
  const int lr = lane & 15, lg = lane >> 4;
  const int wid = tid >> 6;
  const int wr = wid >> 1, wc = wid & 1;

  f32x4 acc[4][4];
#pragma unroll
  for (int m = 0; m < 4; ++m)
#pragma unroll
    for (int n = 0; n < 4; ++n) acc[m][n] = (f32x4){0.f, 0.f, 0.f, 0.f};

  const int nk = K >> 5;
  int cur = 0;
#pragma unroll
  for (int p = 0; p < 2; ++p) {
    int c = p * 256 + tid;
    int row = c >> 2, col = (c & 3) << 3;
    async16(A + (size_t)(m0 + row) * lda + col, &As[0][row * 32 + col]);
    async16(Bt + (size_t)(n0 + row) * ldb + col, &Bs[0][row * 32 + col]);
  }
  __syncthreads();

  for (int t = 0; t < nk; ++t) {
    if (t + 1 < nk) {
      const int k0 = (t + 1) << 5;
#pragma unroll
      for (int p = 0; p < 2; ++p) {
        int c = p * 256 + tid;
        int row = c >> 2, col = (c & 3) << 3;
        async16(A + (size_t)(m0 + row) * lda + k0 + col, &As[cur ^ 1][row * 32 + col]);
        async16(Bt + (size_t)(n0 + row) * ldb + k0 + col, &Bs[cur ^ 1][row * 32 + col]);
      }
    }
    bf16x8 af[4], bfr[4];
#pragma unroll
    for (int m = 0; m < 4; ++m)
      af[m] = *(const bf16x8*)&As[cur][(wr * 64 + m * 16 + lr) * 32 + lg * 8];
#pragma unroll
    for (int n = 0; n < 4; ++n)
      bfr[n] = *(const bf16x8*)&Bs[cur][(wc * 64 + n * 16 + lr) * 32 + lg * 8];
#pragma unroll
    for (int m = 0; m < 4; ++m)
#pragma unroll
      for (int n = 0; n < 4; ++n)
        acc[m][n] = mfma_bf16(af[m], bfr[n], acc[m][n]);
    __syncthreads();
    cur ^= 1;
  }

#pragma unroll
  for (int n = 0; n < 4; ++n) {
    const int col = n0 + wc * 64 + n * 16 + lr;
    const float bv = bias ? bias[col] : 0.0f;
#pragma unroll
    for (int m = 0; m < 4; ++m) {
      const int row = m0 + wr * 64 + m * 16 + lg * 4;
#pragma unroll
      for (int r = 0; r < 4; ++r)
        C[(size_t)(row + r) * ldc + col] = (OT)(acc[m][n][r] + bv);
    }
  }
}

// ---------------------------------------------------------------- attention
// LDS-staged flash attention. 512 blocks x 4 waves.
// Block = one 64-row q-band of (b,h); waves own 16 rows each; band pairing
// (slot j then 15-j) => every block does exactly 17 key-tiles total.
// Per tile: 4 waves cooperatively async-stage K (pre-swizzled per-lane
// global src -> linear LDS dest) and V (fragment-linear vfrag, contiguous)
// into double-buffered LDS; ONE barrier per tile; fragments read as
// conflict-free ds_read_b128. XCD decode keeps each (b,h) on one XCD.
__global__ __launch_bounds__(256) void attn_kernel(
    const bf16_t* __restrict__ qkv, const bf16_t* __restrict__ vfrag,
    bf16_t* __restrict__ o)
{
  __shared__ __align__(16) bf16_t Ks[2][8][512];
  __shared__ __align__(16) bf16_t Vs[2][8][512];
  __shared__ __align__(16) bf16_t Ps[4][16][72];
  const int LD = 3072;
  const bf16_t* q = qkv;
  const bf16_t* k = qkv + 1024;

  const int raw = blockIdx.x;
  const int xcd = raw & 7, idx = raw >> 3;
  const int bh   = (idx >> 3) * 8 + xcd;   // all 8 blocks of a bh on one XCD
  const int slot = idx & 7;                // band pair slot in [0,8)
  const int b = bh >> 4, h = bh & 15;

  const int tid = threadIdx.x;
  const int lane = tid & 63;
  const int lr = lane & 15, lg = lane >> 4;
  const int w = tid >> 6;

  const bf16_t* kbase = k + (size_t)(b * T_) * LD + h * 64;
  const bf16_t* vfbase = vfrag + (size_t)bh * 16 * 8 * 512;

  // wave w stages chunks w*4 .. w*4+3 of the 16 (8 K + 8 V) 1-KB chunks
  auto stage = [&](int bf, int it) {
    const int kv0 = it << 6;
#pragma unroll
    for (int cc = 0; cc < 4; ++cc) {
      const int c = w * 4 + cc;
      if (c < 8) {
        const int kg = c >> 1, kk = c & 1;
        async16(kbase + (size_t)(kv0 + kg * 16 + lr) * LD + kk * 32 + lg * 8,
                &Ks[bf][c][lane * 8]);
      } else {
        const int cv = c - 8;
        async16(vfbase + ((size_t)it * 8 + cv) * 512 + lane * 8,
                &Vs[bf][cv][lane * 8]);
      }
    }
  };

#pragma unroll
  for (int pass = 0; pass < 2; ++pass) {
    const int band = pass ? (15 - slot) : slot;   // 64-row q-band
    const int myq = band * 64 + w * 16 + lr;
    const int nIter = band + 1;

    bf16x8 qf[2];
    {
      const size_t qr = (size_t)(b * T_ + myq) * LD + h * 64;
      qf[0] = *(const bf16x8*)&q[qr + lg * 8];
      qf[1] = *(const bf16x8*)&q[qr + 32 + lg * 8];
    }

    float mi = -3.0e38f, li = 0.0f;
    f32x4 acc[4];
#pragma unroll
    for (int nf = 0; nf < 4; ++nf) acc[nf] = (f32x4){0.f, 0.f, 0.f, 0.f};

    stage(0, 0);
    __syncthreads();

    for (int it = 0; it < nIter; ++it) {
      const int bf = it & 1;
      if (it + 1 < nIter) stage(bf ^ 1, it + 1);
      const int kv0 = it << 6;

      // QK^T from LDS K fragments (kf dead after this cluster)
      f32x4 sfr[4];
      __builtin_amdgcn_s_setprio(1);
#pragma unroll
      for (int kg = 0; kg < 4; ++kg) {
        bf16x8 kf0 = *(const bf16x8*)&Ks[bf][kg * 2 + 0][lane * 8];
        bf16x8 kf1 = *(const bf16x8*)&Ks[bf][kg * 2 + 1][lane * 8];
        f32x4 z = (f32x4){0.f, 0.f, 0.f, 0.f};
        z = mfma_bf16(kf0, qf[0], z);
        z = mfma_bf16(kf1, qf[1], z);
        sfr[kg] = z;
      }
      __builtin_amdgcn_s_setprio(0);

      // scale (net 1/64), causal mask; ILP max/sum trees
      float sv[4][4];
      float pm[4];
#pragma unroll
      for (int kg = 0; kg < 4; ++kg) {
        const int keyb = kv0 + kg * 16 + lg * 4;
        pm[kg] = -3.0e38f;
#pragma unroll
        for (int r = 0; r < 4; ++r) {
          float xx = sfr[kg][r] * 0.015625f;
          if (keyb + r > myq) xx = -3.0e38f;
          sv[kg][r] = xx;
          pm[kg] = fmaxf(pm[kg], xx);
        }
      }
      float pmax = fmaxf(fmaxf(pm[0], pm[1]), fmaxf(pm[2], pm[3]));
      pmax = fmaxf(pmax, __shfl_xor(pmax, 16));
      pmax = fmaxf(pmax, __shfl_xor(pmax, 32));
      const float mnew = fmaxf(mi, pmax);
      const float fr = __expf(mi - mnew);
      mi = mnew;
      float ps[4];
#pragma unroll
      for (int kg = 0; kg < 4; ++kg) {
        float p0 = __expf(sv[kg][0] - mi);
        float p1 = __expf(sv[kg][1] - mi);
        float p2 = __expf(sv[kg][2] - mi);
        float p3 = __expf(sv[kg][3] - mi);
        sv[kg][0] = p0; sv[kg][1] = p1; sv[kg][2] = p2; sv[kg][3] = p3;
        ps[kg] = (p0 + p1) + (p2 + p3);
      }
      float psum = (ps[0] + ps[1]) + (ps[2] + ps[3]);
      psum += __shfl_xor(psum, 16);
      psum += __shfl_xor(psum, 32);
      li = li * fr + psum;
#pragma unroll
      for (int nf = 0; nf < 4; ++nf)
#pragma unroll
        for (int r = 0; r < 4; ++r) acc[nf][r] *= fr;

      // P -> LDS (within-wave round trip)
#pragma unroll
      for (int kg = 0; kg < 4; ++kg) {
        bf16x4 p4;
#pragma unroll
        for (int r = 0; r < 4; ++r) p4[r] = (bf16_t)sv[kg][r];
        *(bf16x4*)&Ps[w][lr][kg * 16 + lg * 4] = p4;
      }

      // O^T += V^T @ P^T from LDS V fragments
      __builtin_amdgcn_s_setprio(1);
#pragma unroll
      for (int kk = 0; kk < 2; ++kk) {
        bf16x8 pf = *(const bf16x8*)&Ps[w][lr][kk * 32 + lg * 8];
#pragma unroll
        for (int nf = 0; nf < 4; ++nf) {
          bf16x8 vf = *(const bf16x8*)&Vs[bf][kk * 4 + nf][lane * 8];
          acc[nf] = mfma_bf16(vf, pf, acc[nf]);
        }
      }
      __builtin_amdgcn_s_setprio(0);

      __syncthreads();   // staged(it+1) complete; all waves done with buf bf
    }

    const float inv = 1.0f / li;
#pragma unroll
    for (int nf = 0; nf < 4; ++nf) {
      bf16x4 o4;
#pragma unroll
      for (int r = 0; r < 4; ++r) o4[r] = (bf16_t)(acc[nf][r] * inv);
      *(bf16x4*)&o[(size_t)(b * T_ + myq) * C_ + h * 64 + nf * 16 + lg * 4] = o4;
    }
  }
}

// ---------------------------------------------------------------- layernorm
__global__ __launch_bounds__(256) void ln_kernel(
    const bf16_t* __restrict__ in,
    const float* __restrict__ g,
    const float* __restrict__ be,
    bf16_t* __restrict__ out)
{
  const int row = blockIdx.x * 4 + (threadIdx.x >> 6);
  const int lane = threadIdx.x & 63;
  const bf16_t* p = in + (size_t)row * C_ + lane * 16;
  bf16x8 a0 = *(const bf16x8*)p;
  bf16x8 a1 = *(const bf16x8*)(p + 8);
  float xs[16];
#pragma unroll
  for (int j = 0; j < 8; ++j) { xs[j] = (float)a0[j]; xs[8 + j] = (float)a1[j]; }
  float sum = 0.f, sq = 0.f;
#pragma unroll
  for (int j = 0; j < 16; ++j) { sum += xs[j]; sq += xs[j] * xs[j]; }
#pragma unroll
  for (int dd = 1; dd < 64; dd <<= 1) {
    sum += __shfl_xor(sum, dd);
    sq  += __shfl_xor(sq, dd);
  }
  const float mean = sum * (1.0f / 1024.0f);
  const float var  = sq * (1.0f / 1024.0f) - mean * mean;
  const float rstd = rsqrtf(var + 1e-5f);
  float gv[16], bv[16];
#pragma unroll
  for (int j = 0; j < 4; ++j) {
    *(float4*)&gv[j * 4] = *(const float4*)(g  + lane * 16 + j * 4);
    *(float4*)&bv[j * 4] = *(const float4*)(be + lane * 16 + j * 4);
  }
  bf16x8 o0, o1;
#pragma unroll
  for (int j = 0; j < 8; ++j) {
    o0[j] = (bf16_t)((xs[j] - mean) * rstd * gv[j] + bv[j]);
    o1[j] = (bf16_t)((xs[8 + j] - mean) * rstd * gv[8 + j] + bv[8 + j]);
  }
  bf16_t* op = out + (size_t)row * C_ + lane * 16;
  *(bf16x8*)op = o0;
  *(bf16x8*)(op + 8) = o1;
}

// ---------------------------------------------------------------- launch
extern "C" void kernel_launch(void* const* d_in, const int* in_sizes, int n_in,
                              void* d_out, int out_size, void* d_ws, size_t ws_size,
                              hipStream_t stream)
{
  const float* x        = (const float*)d_in[0];
  const float* c_attn_w = (const float*)d_in[1];
  const float* c_attn_b = (const float*)d_in[2];
  const float* q_w      = (const float*)d_in[3];
  const float* q_b      = (const float*)d_in[4];
  const float* k_w      = (const float*)d_in[5];
  const float* k_b      = (const float*)d_in[6];
  const float* v_w      = (const float*)d_in[7];
  const float* v_b      = (const float*)d_in[8];
  const float* ln_g     = (const float*)d_in[9];
  const float* ln_b     = (const float*)d_in[10];
  const float* out_w    = (const float*)d_in[11];
  const float* out_b    = (const float*)d_in[12];

  char* ws = (char*)d_ws;
  bf16_t* qkvb      = (bf16_t*)(ws + 0);          // [4096][3072]
  bf16_t* xb        = (bf16_t*)(ws + 25165824);   // [4096][1024] dead after qkv
  bf16_t* lnb       = (bf16_t*)(ws + 25165824);   // overlays xb, used late
  bf16_t* WsT4      = (bf16_t*)(ws + 33554432);   // 4 slabs of 1M bf16
  bf16_t* c_attn_wb = (bf16_t*)(ws + 41943040);   // [1024][3072]
  bf16_t* Wt_eff    = (bf16_t*)(ws + 48234496);   // [3072][1024]
  float*  bias_eff  = (float*)(ws + 54525952);    // [3072]
  bf16_t* vfrag     = (bf16_t*)(ws + 54538240);   // 8 MB fragment-linear V

  convert_f32_bf16<<<dim3(4096), 256, 0, stream>>>(x, xb, 1048576);
  convert_f32_bf16<<<dim3(3072), 256, 0, stream>>>(c_attn_w, c_attn_wb, 786432);

  transpose4_f32_bf16<<<dim3(32, 32, 4), 256, 0, stream>>>(
      q_w, k_w, v_w, out_w, WsT4);

  gemm_bt_bias<bf16_t><<<dim3(192), 256, 0, stream>>>(
      WsT4, 1024, c_attn_wb, 3072, nullptr, Wt_eff, 1024,
      1024, 8, 64, 1 << 20, 1024, 1 << 20);

  hipMemsetAsync(bias_eff, 0, 3072 * sizeof(float), stream);
  bias_eff_kernel<<<dim3(12, 8), 256, 0, stream>>>(
      c_attn_b, q_w, k_w, v_w, q_b, k_b, v_b, bias_eff);

  gemm_bt_bias<bf16_t><<<dim3(768), 256, 0, stream>>>(
      xb, 1024, Wt_eff, 1024, bias_eff, qkvb, 3072, 1024, 24, 768, 0, 0, 0);

  transpose_v<<<dim3(1024), 256, 0, stream>>>(qkvb, vfrag);

  attn_kernel<<<dim3(512), 256, 0, stream>>>(qkvb, vfrag, (bf16_t*)d_out);

  ln_kernel<<<dim3(1024), 256, 0, stream>>>((const bf16_t*)d_out, ln_g, ln_b, lnb);

  gemm_bt_bias<float><<<dim3(256), 256, 0, stream>>>(
      lnb, 1024, WsT4 + (size_t)3 * (1 << 20), 1024, out_b,
      (float*)d_out, 1024, 1024, 8, 256, 0, 0, 0);
}